// Round 9
// baseline (7252.780 us; speedup 1.0000x reference)
//
#include <hip/hip_runtime.h>
#include <cstdint>
#include <cstddef>

#define B_  2
#define S_  2048
#define D_  1024
#define HH_ 4096
#define E_  8
#define RH_ 256

typedef float  f32x4 __attribute__((ext_vector_type(4)));
typedef float  f32x2 __attribute__((ext_vector_type(2)));
typedef __bf16 bf16x8 __attribute__((ext_vector_type(8)));
typedef __bf16 bf16x4 __attribute__((ext_vector_type(4)));

// ---------------------------------------------------------------- helpers
__device__ __forceinline__ void gload_lds16(const void* g, void* l) {
  __builtin_amdgcn_global_load_lds(
      (const __attribute__((address_space(1))) unsigned int*)g,
      (__attribute__((address_space(3))) unsigned int*)l, 16, 0, 0);
}

// stage a 128x64 bf16 tile (row-major, leading dim ldK elems) into LDS linearly
__device__ __forceinline__ void stage128x64(__bf16* s, const __bf16* g, int ldK, int t) {
  const int wv = t >> 6, l = t & 63;
#pragma unroll
  for (int p = 0; p < 4; ++p) {
    const int base = p * 256 + wv * 64;      // wave-uniform flat base
    const int flat = base + l;               // per-lane
    const int row = flat >> 3, c16 = flat & 7;
    gload_lds16(g + (size_t)row * ldK + c16 * 8, s + (size_t)base * 8);
  }
}

// stage a 128x64 tile from F32 source, converting to bf16 (RNE) via registers.
// Produces the same row-major [128][64] LDS layout as stage128x64.
__device__ __forceinline__ void stage128x64_cvt(__bf16* s, const float* g, int ldK, int t) {
#pragma unroll
  for (int p = 0; p < 4; ++p) {
    const int flat = p * 256 + t;
    const int row = flat >> 3, c8 = (flat & 7) << 3;
    const float* src = g + (size_t)row * ldK + c8;
    f32x4 a = *(const f32x4*)src;
    f32x4 b = *(const f32x4*)(src + 4);
    bf16x8 o;
#pragma unroll
    for (int j2 = 0; j2 < 4; ++j2) { o[j2] = (__bf16)a[j2]; o[4 + j2] = (__bf16)b[j2]; }
    *(bf16x8*)&s[(size_t)flat * 8] = o;
  }
}

__device__ __forceinline__ void mfma_tile(const __bf16* sA, const __bf16* sB,
                                          f32x4 acc[4][4], int t) {
  const int w = t >> 6, l = t & 63;
  const int wr = w >> 1, wc = w & 1;
  const int fr = l & 15, fk = (l >> 4) * 8;
#pragma unroll
  for (int kk = 0; kk < 2; ++kk) {
    bf16x8 a[4], b[4];
#pragma unroll
    for (int m = 0; m < 4; ++m)
      a[m] = *(const bf16x8*)&sA[(64 * wr + 16 * m + fr) * 64 + kk * 32 + fk];
#pragma unroll
    for (int n = 0; n < 4; ++n)
      b[n] = *(const bf16x8*)&sB[(64 * wc + 16 * n + fr) * 64 + kk * 32 + fk];
#pragma unroll
    for (int m = 0; m < 4; ++m)
#pragma unroll
      for (int n = 0; n < 4; ++n)
        acc[m][n] = __builtin_amdgcn_mfma_f32_16x16x32_bf16(a[m], b[n], acc[m][n], 0, 0, 0);
  }
}

__device__ __forceinline__ void mfma_tile2(const __bf16* sA, const __bf16* sB,
                                           const __bf16* sC, f32x4 accg[4][4],
                                           f32x4 accu[4][4], int t) {
  const int w = t >> 6, l = t & 63;
  const int wr = w >> 1, wc = w & 1;
  const int fr = l & 15, fk = (l >> 4) * 8;
#pragma unroll
  for (int kk = 0; kk < 2; ++kk) {
    bf16x8 a[4], bg[4], bu[4];
#pragma unroll
    for (int m = 0; m < 4; ++m)
      a[m] = *(const bf16x8*)&sA[(64 * wr + 16 * m + fr) * 64 + kk * 32 + fk];
#pragma unroll
    for (int n = 0; n < 4; ++n) {
      bg[n] = *(const bf16x8*)&sB[(64 * wc + 16 * n + fr) * 64 + kk * 32 + fk];
      bu[n] = *(const bf16x8*)&sC[(64 * wc + 16 * n + fr) * 64 + kk * 32 + fk];
    }
#pragma unroll
    for (int m = 0; m < 4; ++m)
#pragma unroll
      for (int n = 0; n < 4; ++n) {
        accg[m][n] = __builtin_amdgcn_mfma_f32_16x16x32_bf16(a[m], bg[n], accg[m][n], 0, 0, 0);
        accu[m][n] = __builtin_amdgcn_mfma_f32_16x16x32_bf16(a[m], bu[n], accu[m][n], 0, 0, 0);
      }
  }
}

// packed f32 FMA: d = a*b + d (2 lanes of f32 per instruction)
__device__ __forceinline__ f32x2 pkfma(f32x2 a, f32x2 b, f32x2 d) {
  asm("v_pk_fma_f32 %0, %1, %2, %0" : "+v"(d) : "v"(a), "v"(b));
  return d;
}

// inline HW transcendentals (no libm calls)
__device__ __forceinline__ float fexp(float x) {
  return __builtin_amdgcn_exp2f(x * 1.44269504088896f);
}
__device__ __forceinline__ float fsig(float x) {
  return __builtin_amdgcn_rcpf(1.f + fexp(-x));
}
__device__ __forceinline__ float ftanh(float x) {
  return 1.f - 2.f * __builtin_amdgcn_rcpf(fexp(2.f * x) + 1.f);
}

// coherent 16B load (bypass L1/L2 -> coherence point), for data-as-flag polls
__device__ __forceinline__ f32x4 load_cc16(const float* p) {
  f32x4 r;
  asm volatile("global_load_dwordx4 %0, %1, off sc0 sc1\n\ts_waitcnt vmcnt(0)"
               : "=&v"(r) : "v"(p) : "memory");
  return r;
}

// ---------------------------------------------------------------- conversions
// 3-way split: src = hi + mid + lo to ~26 mantissa bits
__global__ void k_split3(const float* __restrict__ src, __bf16* __restrict__ hi,
                         __bf16* __restrict__ mid, __bf16* __restrict__ lo, int n4) {
  int i = blockIdx.x * 256 + threadIdx.x;
  if (i >= n4) return;
  f32x4 v = ((const f32x4*)src)[i];
  bf16x4 h, m, l;
#pragma unroll
  for (int j = 0; j < 4; ++j) {
    float x = v[j];
    __bf16 hb = (__bf16)x;
    float r1 = x - (float)hb;
    __bf16 mb = (__bf16)r1;
    float r2 = r1 - (float)mb;
    h[j] = hb; m[j] = mb; l[j] = (__bf16)r2;
  }
  ((bf16x4*)hi)[i] = h; ((bf16x4*)mid)[i] = m; ((bf16x4*)lo)[i] = l;
}

// ---------------------------------------------------------------- gi GEMM
// gi = x @ W_ih^T + b_ih ; 6 split-pass pairs -> ~f32-exact. M=4096 N=768 K=1024
__global__ __launch_bounds__(256, 2)
void k_gemm_gi(const __bf16* __restrict__ xh, const __bf16* __restrict__ xm,
               const __bf16* __restrict__ xl, const __bf16* __restrict__ wh,
               const __bf16* __restrict__ wm, const __bf16* __restrict__ wl,
               const float* __restrict__ bih, float* __restrict__ gi) {
  __shared__ __bf16 sA[128 * 64], sB[128 * 64];
  const int t = threadIdx.x;
  const int m0 = blockIdx.x * 128, n0 = blockIdx.y * 128;
  f32x4 acc[4][4] = {};
  const __bf16* As[6] = {xh, xh, xm, xh, xm, xl};
  const __bf16* Bs[6] = {wh, wm, wh, wl, wm, wh};
  for (int p = 0; p < 6; ++p) {
    const __bf16* A = As[p];
    const __bf16* Bm = Bs[p];
    for (int kt = 0; kt < D_ / 64; ++kt) {
      __syncthreads();
      stage128x64(sA, A + (size_t)m0 * D_ + kt * 64, D_, t);
      stage128x64(sB, Bm + (size_t)n0 * D_ + kt * 64, D_, t);
      __syncthreads();
      mfma_tile(sA, sB, acc, t);
    }
  }
  const int w = t >> 6, l = t & 63, wr = w >> 1, wc = w & 1;
  const int col = l & 15, rb = (l >> 4) * 4;
#pragma unroll
  for (int m = 0; m < 4; ++m)
#pragma unroll
    for (int n = 0; n < 4; ++n)
#pragma unroll
      for (int i = 0; i < 4; ++i) {
        int gm = m0 + 64 * wr + 16 * m + rb + i;
        int gn = n0 + 64 * wc + 16 * n + col;
        gi[(size_t)gm * 768 + gn] = acc[m][n][i] + bih[gn];
      }
}

// ---------------------------------------------------------------- GRU scan v9
// 8 WGs x 512 thr; WG owns 32 units, 96 f32 W_hh rows LDS-resident (98 KB).
// Conflict-free by construction: col-slice c owns interleaved f32x4 word-chunks
// {4c+64j, j=0..3}; bank(row*260+4c+64j) spreads every 8 consecutive lanes
// across starting banks 0,4,...,28 (exact 32-bank tiling). One weight pass
// serves both batches. Exchange: data-as-flag on NaN-poisoned hs; producers
// atomic-store (agent) BEFORE any poll; 112 pollers each spin one coherent
// 16B load (4x fewer coherent ops than round 8, 4 floats per fetch).
__global__ __launch_bounds__(512, 1)
void k_scan(const float* __restrict__ Whh, const float* __restrict__ gi,
            const float* __restrict__ bhh, float* __restrict__ hs,
            float* __restrict__ newh) {
  if (blockIdx.x & 7) return;
  const int wg = blockIdx.x >> 3;      // 0..7
  const int t = threadIdx.x;
  const int c = t & 15;                // col-slice id
  const int q = t >> 4;                // local unit 0..31
  const int g = wg * 32 + q;           // owned global unit

  __shared__ __align__(16) float wlds[96 * 260];   // 3 gates x 32 units (+pad)
  __shared__ __align__(16) float hbuf[2][2][256];  // [batch][cur/nxt][unit]

  // ---- stage this WG's 96 W_hh rows into LDS (once) ----
  for (int k = t; k < 96 * 64; k += 512) {
    const int r = k >> 6;              // local row 0..95
    const int c4 = (k & 63) << 2;      // col word 0,4,...,252
    const int gate = r >> 5, ql = r & 31;
    const f32x4 v = *(const f32x4*)(Whh + (size_t)(gate * 256 + wg * 32 + ql) * 256 + c4);
    *(f32x4*)&wlds[r * 260 + c4] = v;
  }
  const float bh0 = bhh[g], bh1 = bhh[g + 256], bh2 = bhh[g + 512];
  if (t < 256) { hbuf[0][0][t] = 0.f; hbuf[1][0][t] = 0.f; }
  float h_old0 = 0.f, h_old1 = 0.f;    // replicated across the 16 c-lanes
  const float* gi0 = gi;
  const float* gi1 = gi + (size_t)S_ * 768;
  float ir0 = gi0[g], iz0 = gi0[g + 256], in0 = gi0[g + 512];
  float ir1 = gi1[g], iz1 = gi1[g + 256], in1 = gi1[g + 512];
  const float* w0r = &wlds[q * 260];
  const float* w1r = &wlds[(32 + q) * 260];
  const float* w2r = &wlds[(64 + q) * 260];
  __syncthreads();

  for (int s = 0; s < S_; ++s) {
    const int cur = s & 1, nxt = cur ^ 1;
    const int sn = (s + 1 < S_) ? s + 1 : s;
    const float ir0n = gi0[(size_t)sn * 768 + g];
    const float iz0n = gi0[(size_t)sn * 768 + g + 256];
    const float in0n = gi0[(size_t)sn * 768 + g + 512];
    const float ir1n = gi1[(size_t)sn * 768 + g];
    const float iz1n = gi1[(size_t)sn * 768 + g + 256];
    const float in1n = gi1[(size_t)sn * 768 + g + 512];

    // one weight pass feeds both batches; interleaved chunks = conflict-free
    f32x2 a00 = {0.f, 0.f}, a10 = a00, a20 = a00;  // batch 0: r,z,n
    f32x2 a01 = a00, a11 = a00, a21 = a00;         // batch 1
#pragma unroll
    for (int j = 0; j < 4; ++j) {
      const int col = 4 * c + 64 * j;
      const f32x4 w0v = *(const f32x4*)&w0r[col];
      const f32x4 w1v = *(const f32x4*)&w1r[col];
      const f32x4 w2v = *(const f32x4*)&w2r[col];
      const f32x4 h0v = *(const f32x4*)&hbuf[0][cur][col];
      const f32x4 h1v = *(const f32x4*)&hbuf[1][cur][col];
      const f32x2 w0A = {w0v[0], w0v[1]}, w0B = {w0v[2], w0v[3]};
      const f32x2 w1A = {w1v[0], w1v[1]}, w1B = {w1v[2], w1v[3]};
      const f32x2 w2A = {w2v[0], w2v[1]}, w2B = {w2v[2], w2v[3]};
      const f32x2 h0A = {h0v[0], h0v[1]}, h0B = {h0v[2], h0v[3]};
      const f32x2 h1A = {h1v[0], h1v[1]}, h1B = {h1v[2], h1v[3]};
      a00 = pkfma(w0A, h0A, a00); a00 = pkfma(w0B, h0B, a00);
      a10 = pkfma(w1A, h0A, a10); a10 = pkfma(w1B, h0B, a10);
      a20 = pkfma(w2A, h0A, a20); a20 = pkfma(w2B, h0B, a20);
      a01 = pkfma(w0A, h1A, a01); a01 = pkfma(w0B, h1B, a01);
      a11 = pkfma(w1A, h1A, a11); a11 = pkfma(w1B, h1B, a11);
      a21 = pkfma(w2A, h1A, a21); a21 = pkfma(w2B, h1B, a21);
    }
    float d00 = a00[0] + a00[1], d10 = a10[0] + a10[1], d20 = a20[0] + a20[1];
    float d01 = a01[0] + a01[1], d11 = a11[0] + a11[1], d21 = a21[0] + a21[1];
#pragma unroll
    for (int m = 1; m < 16; m <<= 1) {
      d00 += __shfl_xor(d00, m); d10 += __shfl_xor(d10, m); d20 += __shfl_xor(d20, m);
      d01 += __shfl_xor(d01, m); d11 += __shfl_xor(d11, m); d21 += __shfl_xor(d21, m);
    }
    // batch 0
    {
      const float r = fsig(ir0 + d00 + bh0);
      const float z = fsig(iz0 + d10 + bh1);
      const float n = ftanh(in0 + r * (d20 + bh2));
      const float hn = (1.f - z) * n + z * h_old0;
      h_old0 = hn;
      if (c == 0) {
        hbuf[0][nxt][g] = hn;
        __hip_atomic_store(&hs[((size_t)s * 2 + 0) * 256 + g], hn,
                           __ATOMIC_RELAXED, __HIP_MEMORY_SCOPE_AGENT);
        if (s == S_ - 1) newh[g] = hn;
      }
    }
    // batch 1
    {
      const float r = fsig(ir1 + d01 + bh0);
      const float z = fsig(iz1 + d11 + bh1);
      const float n = ftanh(in1 + r * (d21 + bh2));
      const float hn = (1.f - z) * n + z * h_old1;
      h_old1 = hn;
      if (c == 0) {
        hbuf[1][nxt][g] = hn;
        __hip_atomic_store(&hs[((size_t)s * 2 + 1) * 256 + g], hn,
                           __ATOMIC_RELAXED, __HIP_MEMORY_SCOPE_AGENT);
        if (s == S_ - 1) newh[256 + g] = hn;
      }
    }
    // pull the 224 remote units per batch as 16B chunks (data IS the flag)
    if (t < 112) {
      const int bb = t & 1;
      const int cj = t >> 1;                        // 0..55
      const int rb = 4 * cj + (4 * cj >= wg * 32 ? 32 : 0);
      const float* src = &hs[((size_t)s * 2 + bb) * 256 + rb];
      f32x4 v;
      do {
        v = load_cc16(src);
      } while (v[0] != v[0] || v[1] != v[1] || v[2] != v[2] || v[3] != v[3]);
      *(f32x4*)&hbuf[bb][nxt][rb] = v;
    }
    ir0 = ir0n; iz0 = iz0n; in0 = in0n;
    ir1 = ir1n; iz1 = iz1n; in1 = in1n;
    __syncthreads();
  }
}

// ---------------------------------------------------------------- logits
__global__ void k_logits(const float* __restrict__ hs, const float* __restrict__ Wr,
                         const float* __restrict__ br, float* __restrict__ logits) {
  const int idx = blockIdx.x * 256 + threadIdx.x;  // 32768
  const int tok = idx >> 3, e = idx & 7;
  const int s = tok & (S_ - 1), b = tok >> 11;
  const f32x4* h4 = (const f32x4*)&hs[((size_t)s * 2 + b) * 256];
  const f32x4* w4 = (const f32x4*)&Wr[e * 256];
  float acc = 0.f;
#pragma unroll 8
  for (int k = 0; k < 64; ++k) {
    f32x4 a = h4[k], w = w4[k];
    acc += a[0] * w[0] + a[1] * w[1] + a[2] * w[2] + a[3] * w[3];
  }
  logits[idx] = acc + br[e];
}

// ---------------------------------------------------------------- router finish
__global__ void k_finish(const float* __restrict__ logits, float* __restrict__ wdense,
                         float* __restrict__ partials) {
  const int tok = blockIdx.x * 256 + threadIdx.x;  // 4096
  float p[8];
  float mx = -1e30f;
#pragma unroll
  for (int e = 0; e < 8; ++e) { p[e] = logits[tok * 8 + e]; mx = fmaxf(mx, p[e]); }
  float sum = 0.f;
#pragma unroll
  for (int e = 0; e < 8; ++e) { p[e] = expf(p[e] - mx); sum += p[e]; }
  const float inv = 1.f / sum;
#pragma unroll
  for (int e = 0; e < 8; ++e) p[e] *= inv;
  int i1 = 0;
#pragma unroll
  for (int e = 1; e < 8; ++e) if (p[e] > p[i1]) i1 = e;   // ties -> lower index
  int i2 = -1; float p2 = -1.f;
#pragma unroll
  for (int e = 0; e < 8; ++e) if (e != i1 && p[e] > p2) { p2 = p[e]; i2 = e; }
  const float inv2 = 1.f / (p[i1] + p2);
#pragma unroll
  for (int e = 0; e < 8; ++e)
    wdense[tok * 8 + e] = (e == i1) ? p[i1] * inv2 : (e == i2 ? p2 * inv2 : 0.f);

  __shared__ float ps[256][8];
#pragma unroll
  for (int e = 0; e < 8; ++e) ps[threadIdx.x][e] = p[e];
  __syncthreads();
  for (int st = 128; st >= 1; st >>= 1) {
    if (threadIdx.x < st)
#pragma unroll
      for (int e = 0; e < 8; ++e) ps[threadIdx.x][e] += ps[threadIdx.x + st][e];
    __syncthreads();
  }
  if (threadIdx.x == 0)
#pragma unroll
    for (int e = 0; e < 8; ++e) partials[blockIdx.x * 8 + e] = ps[0][e];
}

__global__ void k_aux(const float* __restrict__ partials, float* __restrict__ aux) {
  __shared__ float m2[8];
  const int e = threadIdx.x;
  if (e < 8) {
    float s = 0.f;
    for (int bl = 0; bl < 16; ++bl) s += partials[bl * 8 + e];
    const float mean = s / 4096.f;
    m2[e] = mean * mean;
  }
  __syncthreads();
  if (threadIdx.x == 0) {
    float s = 0.f;
#pragma unroll
    for (int i = 0; i < 8; ++i) s += m2[i];
    aux[0] = 8.f * s;
  }
}

// ---------------------------------------------------------------- experts
// Weights staged straight from f32 with inline RNE->bf16 conversion (same
// rounding as the old k_tobf4 pass; 24 convert launches + 3 ws buffers gone).
__global__ __launch_bounds__(256, 2)
void k_gateup(const __bf16* __restrict__ xbf, const float* __restrict__ Wg,
              const float* __restrict__ Wu, __bf16* __restrict__ Hbf) {
  __shared__ __bf16 sA[128 * 64], sB[128 * 64], sC[128 * 64];
  const int t = threadIdx.x;
  const int m0 = blockIdx.x * 128, n0 = blockIdx.y * 128;
  f32x4 ag[4][4] = {}, au[4][4] = {};
  for (int kt = 0; kt < D_ / 64; ++kt) {
    __syncthreads();
    stage128x64(sA, xbf + (size_t)m0 * D_ + kt * 64, D_, t);
    stage128x64_cvt(sB, Wg + (size_t)n0 * D_ + kt * 64, D_, t);
    stage128x64_cvt(sC, Wu + (size_t)n0 * D_ + kt * 64, D_, t);
    __syncthreads();
    mfma_tile2(sA, sB, sC, ag, au, t);
  }
  const int w = t >> 6, l = t & 63, wr = w >> 1, wc = w & 1;
  const int col = l & 15, rb = (l >> 4) * 4;
#pragma unroll
  for (int m = 0; m < 4; ++m)
#pragma unroll
    for (int n = 0; n < 4; ++n)
#pragma unroll
      for (int i = 0; i < 4; ++i) {
        int gm = m0 + 64 * wr + 16 * m + rb + i;
        int gn = n0 + 64 * wc + 16 * n + col;
        float gv = ag[m][n][i], uv = au[m][n][i];
        float h = 0.5f * gv * (1.f + erff(gv * 0.70710678118654752440f)) * uv;
        Hbf[(size_t)gm * HH_ + gn] = (__bf16)h;
      }
}

__global__ __launch_bounds__(256, 2)
void k_down(const __bf16* __restrict__ Hbf, const float* __restrict__ Wd,
            const float* __restrict__ wdense, float* __restrict__ out, int e) {
  __shared__ __bf16 sA[128 * 64], sB[128 * 64];
  const int t = threadIdx.x;
  const int m0 = blockIdx.x * 128, n0 = blockIdx.y * 128;
  f32x4 acc[4][4] = {};
  for (int kt = 0; kt < HH_ / 64; ++kt) {
    __syncthreads();
    stage128x64(sA, Hbf + (size_t)m0 * HH_ + kt * 64, HH_, t);
    stage128x64_cvt(sB, Wd + (size_t)n0 * HH_ + kt * 64, HH_, t);
    __syncthreads();
    mfma_tile(sA, sB, acc, t);
  }
  const int w = t >> 6, l = t & 63, wr = w >> 1, wc = w & 1;
  const int col = l & 15, rb = (l >> 4) * 4;
#pragma unroll
  for (int m = 0; m < 4; ++m)
#pragma unroll
    for (int i = 0; i < 4; ++i) {
      const int gm = m0 + 64 * wr + 16 * m + rb + i;
      const float wv = wdense[gm * 8 + e];
#pragma unroll
      for (int n = 0; n < 4; ++n) {
        const int gn = n0 + 64 * wc + 16 * n + col;
        out[(size_t)gm * 1024 + gn] += wv * acc[m][n][i];
      }
    }
}

// ---------------------------------------------------------------- launch
extern "C" void kernel_launch(void* const* d_in, const int* in_sizes, int n_in,
                              void* d_out, int out_size, void* d_ws, size_t ws_size,
                              hipStream_t stream) {
  (void)in_sizes; (void)n_in; (void)out_size; (void)ws_size;
  const float* x    = (const float*)d_in[0];
  const float* Wg   = (const float*)d_in[1];
  const float* Wu   = (const float*)d_in[2];
  const float* Wd   = (const float*)d_in[3];
  const float* Wih  = (const float*)d_in[4];
  const float* Whh  = (const float*)d_in[5];
  const float* bih  = (const float*)d_in[6];
  const float* bhh  = (const float*)d_in[7];
  const float* Wr   = (const float*)d_in[8];
  const float* br   = (const float*)d_in[9];

  float* out    = (float*)d_out;                       // (B,S,D)
  float* logits = out + (size_t)B_ * S_ * D_;          // (B,S,E)
  float* newh   = logits + (size_t)B_ * S_ * E_;       // (B,RH)
  float* aux    = newh + (size_t)B_ * RH_;             // scalar

  char* ws = (char*)d_ws;
  size_t off = 0;
  auto alloc = [&](size_t bytes) { size_t r = off; off += (bytes + 255) & ~(size_t)255; return r; };
  const size_t XN = (size_t)B_ * S_ * D_;              // 4,194,304
  const size_t WIN = (size_t)3 * RH_ * D_;             // 786,432

  __bf16* xh  = (__bf16*)(ws + alloc(XN * 2));
  __bf16* xm  = (__bf16*)(ws + alloc(XN * 2));
  __bf16* xl  = (__bf16*)(ws + alloc(XN * 2));
  __bf16* wih_h = (__bf16*)(ws + alloc(WIN * 2));
  __bf16* wih_m = (__bf16*)(ws + alloc(WIN * 2));
  __bf16* wih_l = (__bf16*)(ws + alloc(WIN * 2));
  float*  gi  = (float*)(ws + alloc((size_t)B_ * S_ * 768 * 4));
  float*  hs  = (float*)(ws + alloc((size_t)S_ * B_ * RH_ * 4));
  float*  wdense = (float*)(ws + alloc((size_t)B_ * S_ * E_ * 4));
  float*  partials = (float*)(ws + alloc(16 * 8 * 4));
  __bf16* Hbf  = (__bf16*)(ws + alloc((size_t)B_ * S_ * HH_ * 2));

  hipMemsetAsync(out, 0, XN * 4, stream);
  // NaN-poison hs: the data-as-flag protocol's "not yet written" marker
  hipMemsetAsync(hs, 0xFF, (size_t)S_ * B_ * RH_ * 4, stream);

  // splits
  k_split3<<<dim3((XN / 4 + 255) / 256), 256, 0, stream>>>(x, xh, xm, xl, (int)(XN / 4));
  k_split3<<<dim3((WIN / 4 + 255) / 256), 256, 0, stream>>>(Wih, wih_h, wih_m, wih_l, (int)(WIN / 4));

  // gi GEMM (f32-exact via 3-way split)
  k_gemm_gi<<<dim3(32, 6), 256, 0, stream>>>(xh, xm, xl, wih_h, wih_m, wih_l, bih, gi);

  // sequential GRU scan (blocks 0,8,...,56 active)
  k_scan<<<dim3(57), 512, 0, stream>>>(Whh, gi, bhh, hs, newh);

  // router outputs
  k_logits<<<dim3(128), 256, 0, stream>>>(hs, Wr, br, logits);
  k_finish<<<dim3(16), 256, 0, stream>>>(logits, wdense, partials);
  k_aux<<<dim3(1), 64, 0, stream>>>(partials, aux);

  // dense experts (bf16 MFMA, inline f32->bf16 weight staging)
  for (int e = 0; e < E_; ++e) {
    const size_t wo = (size_t)e * HH_ * D_;
    k_gateup<<<dim3(32, 32), 256, 0, stream>>>(xh, Wg + wo, Wu + wo, Hbf);
    k_down<<<dim3(32, 8), 256, 0, stream>>>(Hbf, Wd + wo, wdense, out, e);
  }
}

// Round 11
// 4308.615 us; speedup vs baseline: 1.6833x; 1.6833x over previous
//
#include <hip/hip_runtime.h>
#include <cstdint>
#include <cstddef>

#define B_  2
#define S_  2048
#define D_  1024
#define HH_ 4096
#define E_  8
#define RH_ 256

typedef float  f32x4 __attribute__((ext_vector_type(4)));
typedef float  f32x2 __attribute__((ext_vector_type(2)));
typedef __bf16 bf16x8 __attribute__((ext_vector_type(8)));
typedef __bf16 bf16x4 __attribute__((ext_vector_type(4)));

// ---------------------------------------------------------------- helpers
__device__ __forceinline__ void gload_lds16(const void* g, void* l) {
  __builtin_amdgcn_global_load_lds(
      (const __attribute__((address_space(1))) unsigned int*)g,
      (__attribute__((address_space(3))) unsigned int*)l, 16, 0, 0);
}

// stage a 128x64 bf16 tile (row-major, leading dim ldK elems) into LDS linearly
__device__ __forceinline__ void stage128x64(__bf16* s, const __bf16* g, int ldK, int t) {
  const int wv = t >> 6, l = t & 63;
#pragma unroll
  for (int p = 0; p < 4; ++p) {
    const int base = p * 256 + wv * 64;      // wave-uniform flat base
    const int flat = base + l;               // per-lane
    const int row = flat >> 3, c16 = flat & 7;
    gload_lds16(g + (size_t)row * ldK + c16 * 8, s + (size_t)base * 8);
  }
}

__device__ __forceinline__ void mfma_tile(const __bf16* sA, const __bf16* sB,
                                          f32x4 acc[4][4], int t) {
  const int w = t >> 6, l = t & 63;
  const int wr = w >> 1, wc = w & 1;
  const int fr = l & 15, fk = (l >> 4) * 8;
#pragma unroll
  for (int kk = 0; kk < 2; ++kk) {
    bf16x8 a[4], b[4];
#pragma unroll
    for (int m = 0; m < 4; ++m)
      a[m] = *(const bf16x8*)&sA[(64 * wr + 16 * m + fr) * 64 + kk * 32 + fk];
#pragma unroll
    for (int n = 0; n < 4; ++n)
      b[n] = *(const bf16x8*)&sB[(64 * wc + 16 * n + fr) * 64 + kk * 32 + fk];
#pragma unroll
    for (int m = 0; m < 4; ++m)
#pragma unroll
      for (int n = 0; n < 4; ++n)
        acc[m][n] = __builtin_amdgcn_mfma_f32_16x16x32_bf16(a[m], b[n], acc[m][n], 0, 0, 0);
  }
}

__device__ __forceinline__ void mfma_tile2(const __bf16* sA, const __bf16* sB,
                                           const __bf16* sC, f32x4 accg[4][4],
                                           f32x4 accu[4][4], int t) {
  const int w = t >> 6, l = t & 63;
  const int wr = w >> 1, wc = w & 1;
  const int fr = l & 15, fk = (l >> 4) * 8;
#pragma unroll
  for (int kk = 0; kk < 2; ++kk) {
    bf16x8 a[4], bg[4], bu[4];
#pragma unroll
    for (int m = 0; m < 4; ++m)
      a[m] = *(const bf16x8*)&sA[(64 * wr + 16 * m + fr) * 64 + kk * 32 + fk];
#pragma unroll
    for (int n = 0; n < 4; ++n) {
      bg[n] = *(const bf16x8*)&sB[(64 * wc + 16 * n + fr) * 64 + kk * 32 + fk];
      bu[n] = *(const bf16x8*)&sC[(64 * wc + 16 * n + fr) * 64 + kk * 32 + fk];
    }
#pragma unroll
    for (int m = 0; m < 4; ++m)
#pragma unroll
      for (int n = 0; n < 4; ++n) {
        accg[m][n] = __builtin_amdgcn_mfma_f32_16x16x32_bf16(a[m], bg[n], accg[m][n], 0, 0, 0);
        accu[m][n] = __builtin_amdgcn_mfma_f32_16x16x32_bf16(a[m], bu[n], accu[m][n], 0, 0, 0);
      }
  }
}

// packed f32 FMA: d = a*b + d (2 lanes of f32 per instruction)
__device__ __forceinline__ f32x2 pkfma(f32x2 a, f32x2 b, f32x2 d) {
  asm("v_pk_fma_f32 %0, %1, %2, %0" : "+v"(d) : "v"(a), "v"(b));
  return d;
}

// inline HW transcendentals (no libm calls -> no call serialization; r5->r6
// measured -19% on the scan at identical structure)
__device__ __forceinline__ float fexp(float x) {
  return __builtin_amdgcn_exp2f(x * 1.44269504088896f);
}
__device__ __forceinline__ float fsig(float x) {
  return __builtin_amdgcn_rcpf(1.f + fexp(-x));
}
__device__ __forceinline__ float ftanh(float x) {
  return 1.f - 2.f * __builtin_amdgcn_rcpf(fexp(2.f * x) + 1.f);
}

// ---------------------------------------------------------------- conversions
// 3-way split: src = hi + mid + lo to ~26 mantissa bits
__global__ void k_split3(const float* __restrict__ src, __bf16* __restrict__ hi,
                         __bf16* __restrict__ mid, __bf16* __restrict__ lo, int n4) {
  int i = blockIdx.x * 256 + threadIdx.x;
  if (i >= n4) return;
  f32x4 v = ((const f32x4*)src)[i];
  bf16x4 h, m, l;
#pragma unroll
  for (int j = 0; j < 4; ++j) {
    float x = v[j];
    __bf16 hb = (__bf16)x;
    float r1 = x - (float)hb;
    __bf16 mb = (__bf16)r1;
    float r2 = r1 - (float)mb;
    h[j] = hb; m[j] = mb; l[j] = (__bf16)r2;
  }
  ((bf16x4*)hi)[i] = h; ((bf16x4*)mid)[i] = m; ((bf16x4*)lo)[i] = l;
}

__global__ void k_tobf4(const float* __restrict__ src, __bf16* __restrict__ dst, int n4) {
  int i = blockIdx.x * 256 + threadIdx.x;
  if (i >= n4) return;
  f32x4 v = ((const f32x4*)src)[i];
  bf16x4 o;
#pragma unroll
  for (int j = 0; j < 4; ++j) o[j] = (__bf16)v[j];
  ((bf16x4*)dst)[i] = o;
}

// ---------------------------------------------------------------- gi GEMM
// gi = x @ W_ih^T + b_ih ; 6 split-pass pairs -> ~f32-exact. M=4096 N=768 K=1024
__global__ __launch_bounds__(256, 2)
void k_gemm_gi(const __bf16* __restrict__ xh, const __bf16* __restrict__ xm,
               const __bf16* __restrict__ xl, const __bf16* __restrict__ wh,
               const __bf16* __restrict__ wm, const __bf16* __restrict__ wl,
               const float* __restrict__ bih, float* __restrict__ gi) {
  __shared__ __bf16 sA[128 * 64], sB[128 * 64];
  const int t = threadIdx.x;
  const int m0 = blockIdx.x * 128, n0 = blockIdx.y * 128;
  f32x4 acc[4][4] = {};
  const __bf16* As[6] = {xh, xh, xm, xh, xm, xl};
  const __bf16* Bs[6] = {wh, wm, wh, wl, wm, wh};
  for (int p = 0; p < 6; ++p) {
    const __bf16* A = As[p];
    const __bf16* Bm = Bs[p];
    for (int kt = 0; kt < D_ / 64; ++kt) {
      __syncthreads();
      stage128x64(sA, A + (size_t)m0 * D_ + kt * 64, D_, t);
      stage128x64(sB, Bm + (size_t)n0 * D_ + kt * 64, D_, t);
      __syncthreads();
      mfma_tile(sA, sB, acc, t);
    }
  }
  const int w = t >> 6, l = t & 63, wr = w >> 1, wc = w & 1;
  const int col = l & 15, rb = (l >> 4) * 4;
#pragma unroll
  for (int m = 0; m < 4; ++m)
#pragma unroll
    for (int n = 0; n < 4; ++n)
#pragma unroll
      for (int i = 0; i < 4; ++i) {
        int gm = m0 + 64 * wr + 16 * m + rb + i;
        int gn = n0 + 64 * wc + 16 * n + col;
        gi[(size_t)gm * 768 + gn] = acc[m][n][i] + bih[gn];
      }
}

// ---------------------------------------------------------------- GRU scan v11
// EXACTLY round 2's measured-fastest scan (1.44 us/step: 4 WGs x 512 thr,
// pairwise batch-partner exchange, deep 8-wave latency hiding over the weight
// stream, agent-scope data-as-flag on NaN-poisoned hs) with ONE change: the
// r5->r6-proven inline transcendentals replace libm expf/tanhf.
__global__ __attribute__((amdgpu_flat_work_group_size(512, 512)))
__attribute__((amdgpu_waves_per_eu(2, 2)))
void k_scan(const float* __restrict__ Whh, const float* __restrict__ gi,
            const float* __restrict__ bhh, float* __restrict__ hs,
            float* __restrict__ newh) {
  int role;
  switch (blockIdx.x) {
    case 0: role = 0; break;   // batch 0, half 0
    case 8: role = 1; break;   // batch 0, half 1
    case 1: role = 2; break;   // batch 1, half 0
    case 9: role = 3; break;   // batch 1, half 1
    default: return;
  }
  const int b = role >> 1, half = role & 1;
  const int t = threadIdx.x;
  const int c = t & 3;                 // col slice: h[64c..64c+63]
  const int q = t >> 2;                // local unit 0..127
  const int g = half * 128 + q;        // global unit 0..255

  __shared__ __align__(16) float hbuf[2][256];

  // weights: rotated chunk order (j+2c)&15 -> conflict-free LDS reads later
  f32x2 w0[32], w1[32], w2[32];
#pragma unroll
  for (int j = 0; j < 16; ++j) {
    const int jr = (j + 2 * c) & 15;
    const size_t colo = (size_t)(64 * c + 4 * jr);
    f32x4 v0 = *(const f32x4*)(Whh + (size_t)g * 256 + colo);
    f32x4 v1 = *(const f32x4*)(Whh + (size_t)(g + 256) * 256 + colo);
    f32x4 v2 = *(const f32x4*)(Whh + (size_t)(g + 512) * 256 + colo);
    w0[2 * j] = f32x2{v0[0], v0[1]}; w0[2 * j + 1] = f32x2{v0[2], v0[3]};
    w1[2 * j] = f32x2{v1[0], v1[1]}; w1[2 * j + 1] = f32x2{v1[2], v1[3]};
    w2[2 * j] = f32x2{v2[0], v2[1]}; w2[2 * j + 1] = f32x2{v2[2], v2[3]};
  }
#pragma unroll
  for (int j = 0; j < 32; ++j) {
    asm("" : "+v"(w0[j]));
    asm("" : "+v"(w1[j]));
    asm("" : "+v"(w2[j]));
  }
  const float bh0 = bhh[g], bh1 = bhh[g + 256], bh2 = bhh[g + 512];
  if (t < 256) hbuf[0][t] = 0.f;
  float h_old = 0.f;                   // replicated across the quad
  const float* giB = gi + (size_t)(b * S_) * 768;
  float* hsB = hs + (size_t)b * 256;   // row stride 512 floats
  // software-pipelined gi loads
  float ir = giB[g], iz = giB[g + 256], in_ = giB[g + 512];
  __syncthreads();

  for (int s = 0; s < S_; ++s) {
    const int cur = s & 1, nxt = cur ^ 1;
    const int sn = (s + 1 < S_) ? s + 1 : s;
    const float irn = giB[(size_t)sn * 768 + g];
    const float izn = giB[(size_t)sn * 768 + g + 256];
    const float inn = giB[(size_t)sn * 768 + g + 512];

    f32x2 a0 = {0.f, 0.f}, a1 = a0, a2 = a0;
#pragma unroll
    for (int j = 0; j < 16; ++j) {
      const int jr = (j + 2 * c) & 15;
      f32x4 hv = *(const f32x4*)&hbuf[cur][64 * c + 4 * jr];
      f32x2 hA = {hv[0], hv[1]}, hB = {hv[2], hv[3]};
      a0 = pkfma(w0[2 * j], hA, a0); a0 = pkfma(w0[2 * j + 1], hB, a0);
      a1 = pkfma(w1[2 * j], hA, a1); a1 = pkfma(w1[2 * j + 1], hB, a1);
      a2 = pkfma(w2[2 * j], hA, a2); a2 = pkfma(w2[2 * j + 1], hB, a2);
    }
    float d0 = (a0[0] + a0[1]);
    float d1 = (a1[0] + a1[1]);
    float d2 = (a2[0] + a2[1]);
    d0 += __shfl_xor(d0, 1); d0 += __shfl_xor(d0, 2);
    d1 += __shfl_xor(d1, 1); d1 += __shfl_xor(d1, 2);
    d2 += __shfl_xor(d2, 1); d2 += __shfl_xor(d2, 2);

    const float r = fsig(ir + d0 + bh0);
    const float z = fsig(iz + d1 + bh1);
    const float n = ftanh(in_ + r * (d2 + bh2));
    const float hn = (1.f - z) * n + z * h_old;
    h_old = hn;

    float* hsrow = hsB + (size_t)s * 512;
    if (c == 0) {
      hbuf[nxt][g] = hn;               // own half for next step (LDS)
      __hip_atomic_store(hsrow + g, hn, __ATOMIC_RELAXED, __HIP_MEMORY_SCOPE_AGENT);
    }
    if (t < 128) {                     // poll partner half: data IS the flag
      const int pg = (half ^ 1) * 128 + t;
      float v;
      do {
        v = __hip_atomic_load(hsrow + pg, __ATOMIC_RELAXED, __HIP_MEMORY_SCOPE_AGENT);
      } while (v != v);                // NaN-poisoned until written
      hbuf[nxt][pg] = v;
    }
    ir = irn; iz = izn; in_ = inn;
    __syncthreads();
  }
  if (c == 0) newh[b * 256 + g] = h_old;
}

// ---------------------------------------------------------------- logits
__global__ void k_logits(const float* __restrict__ hs, const float* __restrict__ Wr,
                         const float* __restrict__ br, float* __restrict__ logits) {
  const int idx = blockIdx.x * 256 + threadIdx.x;  // 32768
  const int tok = idx >> 3, e = idx & 7;
  const int s = tok & (S_ - 1), b = tok >> 11;
  const f32x4* h4 = (const f32x4*)&hs[((size_t)s * 2 + b) * 256];
  const f32x4* w4 = (const f32x4*)&Wr[e * 256];
  float acc = 0.f;
#pragma unroll 8
  for (int k = 0; k < 64; ++k) {
    f32x4 a = h4[k], w = w4[k];
    acc += a[0] * w[0] + a[1] * w[1] + a[2] * w[2] + a[3] * w[3];
  }
  logits[idx] = acc + br[e];
}

// ---------------------------------------------------------------- router finish
__global__ void k_finish(const float* __restrict__ logits, float* __restrict__ wdense,
                         float* __restrict__ partials) {
  const int tok = blockIdx.x * 256 + threadIdx.x;  // 4096
  float p[8];
  float mx = -1e30f;
#pragma unroll
  for (int e = 0; e < 8; ++e) { p[e] = logits[tok * 8 + e]; mx = fmaxf(mx, p[e]); }
  float sum = 0.f;
#pragma unroll
  for (int e = 0; e < 8; ++e) { p[e] = expf(p[e] - mx); sum += p[e]; }
  const float inv = 1.f / sum;
#pragma unroll
  for (int e = 0; e < 8; ++e) p[e] *= inv;
  int i1 = 0;
#pragma unroll
  for (int e = 1; e < 8; ++e) if (p[e] > p[i1]) i1 = e;   // ties -> lower index
  int i2 = -1; float p2 = -1.f;
#pragma unroll
  for (int e = 0; e < 8; ++e) if (e != i1 && p[e] > p2) { p2 = p[e]; i2 = e; }
  const float inv2 = 1.f / (p[i1] + p2);
#pragma unroll
  for (int e = 0; e < 8; ++e)
    wdense[tok * 8 + e] = (e == i1) ? p[i1] * inv2 : (e == i2 ? p2 * inv2 : 0.f);

  __shared__ float ps[256][8];
#pragma unroll
  for (int e = 0; e < 8; ++e) ps[threadIdx.x][e] = p[e];
  __syncthreads();
  for (int st = 128; st >= 1; st >>= 1) {
    if (threadIdx.x < st)
#pragma unroll
      for (int e = 0; e < 8; ++e) ps[threadIdx.x][e] += ps[threadIdx.x + st][e];
    __syncthreads();
  }
  if (threadIdx.x == 0)
#pragma unroll
    for (int e = 0; e < 8; ++e) partials[blockIdx.x * 8 + e] = ps[0][e];
}

__global__ void k_aux(const float* __restrict__ partials, float* __restrict__ aux) {
  __shared__ float m2[8];
  const int e = threadIdx.x;
  if (e < 8) {
    float s = 0.f;
    for (int bl = 0; bl < 16; ++bl) s += partials[bl * 8 + e];
    const float mean = s / 4096.f;
    m2[e] = mean * mean;
  }
  __syncthreads();
  if (threadIdx.x == 0) {
    float s = 0.f;
#pragma unroll
    for (int i = 0; i < 8; ++i) s += m2[i];
    aux[0] = 8.f * s;
  }
}

// ---------------------------------------------------------------- experts
__global__ __launch_bounds__(256, 2)
void k_gateup(const __bf16* __restrict__ xbf, const __bf16* __restrict__ Wgbf,
              const __bf16* __restrict__ Wubf, __bf16* __restrict__ Hbf) {
  __shared__ __bf16 sA[128 * 64], sB[128 * 64], sC[128 * 64];
  const int t = threadIdx.x;
  const int m0 = blockIdx.x * 128, n0 = blockIdx.y * 128;
  f32x4 ag[4][4] = {}, au[4][4] = {};
  for (int kt = 0; kt < D_ / 64; ++kt) {
    __syncthreads();
    stage128x64(sA, xbf + (size_t)m0 * D_ + kt * 64, D_, t);
    stage128x64(sB, Wgbf + (size_t)n0 * D_ + kt * 64, D_, t);
    stage128x64(sC, Wubf + (size_t)n0 * D_ + kt * 64, D_, t);
    __syncthreads();
    mfma_tile2(sA, sB, sC, ag, au, t);
  }
  const int w = t >> 6, l = t & 63, wr = w >> 1, wc = w & 1;
  const int col = l & 15, rb = (l >> 4) * 4;
#pragma unroll
  for (int m = 0; m < 4; ++m)
#pragma unroll
    for (int n = 0; n < 4; ++n)
#pragma unroll
      for (int i = 0; i < 4; ++i) {
        int gm = m0 + 64 * wr + 16 * m + rb + i;
        int gn = n0 + 64 * wc + 16 * n + col;
        float gv = ag[m][n][i], uv = au[m][n][i];
        float h = 0.5f * gv * (1.f + erff(gv * 0.70710678118654752440f)) * uv;
        Hbf[(size_t)gm * HH_ + gn] = (__bf16)h;
      }
}

__global__ __launch_bounds__(256, 2)
void k_down(const __bf16* __restrict__ Hbf, const __bf16* __restrict__ Wdbf,
            const float* __restrict__ wdense, float* __restrict__ out, int e) {
  __shared__ __bf16 sA[128 * 64], sB[128 * 64];
  const int t = threadIdx.x;
  const int m0 = blockIdx.x * 128, n0 = blockIdx.y * 128;
  f32x4 acc[4][4] = {};
  for (int kt = 0; kt < HH_ / 64; ++kt) {
    __syncthreads();
    stage128x64(sA, Hbf + (size_t)m0 * HH_ + kt * 64, HH_, t);
    stage128x64(sB, Wdbf + (size_t)n0 * HH_ + kt * 64, HH_, t);
    __syncthreads();
    mfma_tile(sA, sB, acc, t);
  }
  const int w = t >> 6, l = t & 63, wr = w >> 1, wc = w & 1;
  const int col = l & 15, rb = (l >> 4) * 4;
#pragma unroll
  for (int m = 0; m < 4; ++m)
#pragma unroll
    for (int i = 0; i < 4; ++i) {
      const int gm = m0 + 64 * wr + 16 * m + rb + i;
      const float wv = wdense[gm * 8 + e];
#pragma unroll
      for (int n = 0; n < 4; ++n) {
        const int gn = n0 + 64 * wc + 16 * n + col;
        out[(size_t)gm * 1024 + gn] += wv * acc[m][n][i];
      }
    }
}

// ---------------------------------------------------------------- launch
extern "C" void kernel_launch(void* const* d_in, const int* in_sizes, int n_in,
                              void* d_out, int out_size, void* d_ws, size_t ws_size,
                              hipStream_t stream) {
  (void)in_sizes; (void)n_in; (void)out_size; (void)ws_size;
  const float* x    = (const float*)d_in[0];
  const float* Wg   = (const float*)d_in[1];
  const float* Wu   = (const float*)d_in[2];
  const float* Wd   = (const float*)d_in[3];
  const float* Wih  = (const float*)d_in[4];
  const float* Whh  = (const float*)d_in[5];
  const float* bih  = (const float*)d_in[6];
  const float* bhh  = (const float*)d_in[7];
  const float* Wr   = (const float*)d_in[8];
  const float* br   = (const float*)d_in[9];

  float* out    = (float*)d_out;                       // (B,S,D)
  float* logits = out + (size_t)B_ * S_ * D_;          // (B,S,E)
  float* newh   = logits + (size_t)B_ * S_ * E_;       // (B,RH)
  float* aux    = newh + (size_t)B_ * RH_;             // scalar

  char* ws = (char*)d_ws;
  size_t off = 0;
  auto alloc = [&](size_t bytes) { size_t r = off; off += (bytes + 255) & ~(size_t)255; return r; };
  const size_t XN = (size_t)B_ * S_ * D_;              // 4,194,304
  const size_t WIN = (size_t)3 * RH_ * D_;             // 786,432

  __bf16* xh  = (__bf16*)(ws + alloc(XN * 2));
  __bf16* xm  = (__bf16*)(ws + alloc(XN * 2));
  __bf16* xl  = (__bf16*)(ws + alloc(XN * 2));
  __bf16* wih_h = (__bf16*)(ws + alloc(WIN * 2));
  __bf16* wih_m = (__bf16*)(ws + alloc(WIN * 2));
  __bf16* wih_l = (__bf16*)(ws + alloc(WIN * 2));
  float*  gi  = (float*)(ws + alloc((size_t)B_ * S_ * 768 * 4));
  float*  hs  = (float*)(ws + alloc((size_t)S_ * B_ * RH_ * 4));
  float*  wdense = (float*)(ws + alloc((size_t)B_ * S_ * E_ * 4));
  float*  partials = (float*)(ws + alloc(16 * 8 * 4));
  __bf16* Wgbf = (__bf16*)(ws + alloc((size_t)HH_ * D_ * 2));
  __bf16* Wubf = (__bf16*)(ws + alloc((size_t)HH_ * D_ * 2));
  __bf16* Wdbf = (__bf16*)(ws + alloc((size_t)D_ * HH_ * 2));
  __bf16* Hbf  = (__bf16*)(ws + alloc((size_t)B_ * S_ * HH_ * 2));

  hipMemsetAsync(out, 0, XN * 4, stream);
  // NaN-poison hs: the data-as-flag protocol's "not yet written" marker
  hipMemsetAsync(hs, 0xFF, (size_t)S_ * B_ * RH_ * 4, stream);

  // splits
  k_split3<<<dim3((XN / 4 + 255) / 256), 256, 0, stream>>>(x, xh, xm, xl, (int)(XN / 4));
  k_split3<<<dim3((WIN / 4 + 255) / 256), 256, 0, stream>>>(Wih, wih_h, wih_m, wih_l, (int)(WIN / 4));

  // gi GEMM (f32-exact via 3-way split)
  k_gemm_gi<<<dim3(32, 6), 256, 0, stream>>>(xh, xm, xl, wih_h, wih_m, wih_l, bih, gi);

  // sequential GRU scan (round-2 structure: blocks 0,8 = batch0; 1,9 = batch1)
  k_scan<<<dim3(16), 512, 0, stream>>>(Whh, gi, bhh, hs, newh);

  // router outputs
  k_logits<<<dim3(128), 256, 0, stream>>>(hs, Wr, br, logits);
  k_finish<<<dim3(16), 256, 0, stream>>>(logits, wdense, partials);
  k_aux<<<dim3(1), 64, 0, stream>>>(partials, aux);

  // dense experts (bf16 MFMA), accumulate weighted into out
  const int n4w = (int)((size_t)HH_ * D_ / 4);
  for (int e = 0; e < E_; ++e) {
    k_tobf4<<<dim3((n4w + 255) / 256), 256, 0, stream>>>(Wg + (size_t)e * HH_ * D_, Wgbf, n4w);
    k_tobf4<<<dim3((n4w + 255) / 256), 256, 0, stream>>>(Wu + (size_t)e * HH_ * D_, Wubf, n4w);
    k_tobf4<<<dim3((n4w + 255) / 256), 256, 0, stream>>>(Wd + (size_t)e * D_ * HH_, Wdbf, n4w);
    k_gateup<<<dim3(32, 32), 256, 0, stream>>>(xh, Wgbf, Wubf, Hbf);
    k_down<<<dim3(32, 8), 256, 0, stream>>>(Hbf, Wdbf, wdense, out, e);
  }
}